// Round 6
// baseline (81.396 us; speedup 1.0000x reference)
//
#include <hip/hip_runtime.h>
#include <math.h>

#define M_TOT 87296
#define NMAIN 682           // main blocks, 128 locations each; block NMAIN = pos-terms
#define INF_F 100000000.0f

// ws layout (floats):
//   [0]                  int completion counter (memset to 0 each launch)
//   [1..3]               pad
//   [4        .. 4+NMAIN)    per-block reg_sum
//   [4+NMAIN  .. 4+2*NMAIN)  per-block reg_cnt
//   [4+2N     .. 4+3*NMAIN)  per-block neg_sum
//   [4+3N], [4+3N+1]         psum, pcnt (from pos-terms block)

__global__ __launch_bounds__(256, 2) void fused_kernel(
    const float* __restrict__ boxes,     // [4,64,4]
    const float* __restrict__ agn,       // [M_TOT]
    const float* __restrict__ reg_pred,  // [M_TOT,4]
    float* __restrict__ ws,
    float* __restrict__ out)
{
    __shared__ float4 sBox[256];
    __shared__ float  sRed[16];
    __shared__ int    sLast;

    const int t   = threadIdx.x;
    const int blk = blockIdx.x;

    const int   LB_[5]   = {0, 65536, 81920, 86016, 87040};
    const int   locSh[5] = {14, 12, 10, 8, 6};
    const int   wSh[5]   = {7, 6, 5, 4, 3};
    const float SV[5]    = {8.f, 16.f, 32.f, 64.f, 128.f};
    const float LOv[5]   = {0.f, 64.f, 128.f, 256.f, 512.f};
    const float HIv[5]   = {80.f, 160.f, 320.f, 640.f, 10000000.f};

    if (blk == NMAIN) {
        // ---- pos-terms block (independent of the assignment) ----
        const int   LOC[5] = {16384, 4096, 1024, 256, 64};
        const int   WW[5]  = {128, 64, 32, 16, 8};
        float psum = 0.f, pcnt = 0.f;
        for (int j = t; j < 1280; j += 256) {     // [B,N,L] flattened, L fastest
            const int lev = j % 5;
            const int bn  = j / 5;
            const int b   = bn >> 6;
            const float4 bx = ((const float4*)boxes)[bn];
            const float cx = (bx.x + bx.z) * 0.5f;
            const float cy = (bx.y + bx.w) * 0.5f;
            const int cix = (int)(cx / SV[lev]);
            const int ciy = (int)(cy / SV[lev]);
            int pos = LB_[lev] + b * LOC[lev] + ciy * WW[lev] + cix;
            pos = min(max(pos, 0), M_TOT - 1);
            const float dx = bx.z - bx.x, dy = bx.w - bx.y;
            const float crit = sqrtf(dx * dx + dy * dy) * 0.5f;
            const bool msk = (crit >= LOv[lev]) && (crit <= HIv[lev]);
            const float z = agn[pos];
            float pp = 1.0f / (1.0f + expf(-z));
            pp = fminf(fmaxf(pp, 1e-4f), 1.0f - 1e-4f);
            if (msk) {
                const float om = 1.0f - pp;
                psum += logf(pp) * (om * om);
                pcnt += 1.0f;
            }
        }
        for (int off = 32; off; off >>= 1) {
            psum += __shfl_down(psum, off);
            pcnt += __shfl_down(pcnt, off);
        }
        if ((t & 63) == 0) { sRed[t >> 6] = psum; sRed[4 + (t >> 6)] = pcnt; }
        __syncthreads();
        if (t == 0) {
            ws[4 + 3 * NMAIN]     = sRed[0] + sRed[1] + sRed[2] + sRed[3];
            ws[4 + 3 * NMAIN + 1] = sRed[4] + sRed[5] + sRed[6] + sRed[7];
        }
    } else {
        // ---- main: 128 consecutive locations; 8 subs x 8 boxes x 4 locs per thread ----
        const int mbase = blk << 7;
        int lev;
        if      (mbase < 65536) lev = 0;
        else if (mbase < 81920) lev = 1;
        else if (mbase < 86016) lev = 2;
        else if (mbase < 87040) lev = 3;
        else                    lev = 4;

        const int   LB    = LB_[lev];
        const int   lsh   = locSh[lev];
        const int   wsh   = wSh[lev];
        const float s     = SV[lev];
        const float inv_s = 1.0f / s;      // s is pow2: exact reciprocal
        const float half  = 0.5f * s;
        const float lo    = LOv[lev], hi = HIv[lev];

        sBox[t] = ((const float4*)boxes)[t];     // stage all 256 boxes
        __syncthreads();

        const int g       = t >> 3;              // 32 groups x 4 locations
        const int su      = t & 7;               // sub-lane: boxes su+8k
        const int locBase = mbase + g * 4;       // group's 4 locs lie in ONE image
        const int imgBase = ((locBase - LB) >> lsh) << 6;

        const double DELTA = (1.0 - 0.8) / (1.0 + 0.8);
        const float  RADC  = (float)(DELTA * DELTA * 2.0);

        // register-resident box state; cared hoisted per-box (level-uniform, <=2ulp vs ref)
        float bx1[8], by1[8], bx2[8], by2[8], bcx[8], bcy[8], bqx[8], bqy[8], bir[8];
        int caredMask = 0;
        #pragma unroll
        for (int k = 0; k < 8; ++k) {
            const float4 A = sBox[imgBase + su + 8 * k];
            bx1[k] = A.x; by1[k] = A.y; bx2[k] = A.z; by2[k] = A.w;
            bcx[k] = (A.x + A.z) * 0.5f;
            bcy[k] = (A.y + A.w) * 0.5f;
            bqx[k] = truncf(bcx[k] * inv_s) * s + half;   // int32-trunc semantics, centers>=0
            bqy[k] = truncf(bcy[k] * inv_s) * s + half;
            const float area = (A.z - A.x) * (A.w - A.y);
            bir[k] = 1.0f / fmaxf(RADC * area, 16.0f);
            const float bw = A.z - A.x, bh = A.w - A.y;
            const float crit = sqrtf(bw * bw + bh * bh) * 0.5f;
            caredMask |= ((crit >= lo) && (crit <= hi)) ? (1 << k) : 0;
        }

        float minW[4], bestD[4];
        int   bestN[4];
        #pragma unroll
        for (int j = 0; j < 4; ++j) { minW[j] = INF_F; bestD[j] = INF_F; bestN[j] = 0; }

        #pragma unroll
        for (int j = 0; j < 4; ++j) {
            const int   p  = (locBase + j - LB) & ((1 << lsh) - 1);
            const float gx = (float)(p & ((1 << wsh) - 1)) * s + half;
            const float gy = (float)(p >> wsh) * s + half;
            #pragma unroll
            for (int k = 0; k < 8; ++k) {
                const float l  = gx - bx1[k];
                const float tt = gy - by1[k];
                const float rr = bx2[k] - gx;
                const float bb = by2[k] - gy;
                const bool is_in = fminf(fminf(l, tt), fminf(rr, bb)) > 0.0f;
                const float dx = gx - bqx[k], dy = gy - bqy[k];
                const bool is_peak = (dx * dx + dy * dy) == 0.0f;
                const bool msk = (fabsf(dx) <= s) && (fabsf(dy) <= s) && is_in
                                 && ((caredMask >> k) & 1);
                const float ddx = gx - bcx[k], ddy = gy - bcy[k];
                const float dist2 = is_peak ? 0.0f : (ddx * ddx + ddy * ddy);
                const float w2 = dist2 * bir[k];
                minW[j] = fminf(minW[j], w2);
                const float d = msk ? w2 : INF_F;        // w2 < 1e8 always
                if (d < bestD[j]) { bestD[j] = d; bestN[j] = su + 8 * k; }  // ascending n
            }
        }

        // cross-sub reduce per slot j; lane su==j keeps -> lane covers loc locBase+su (su<4)
        unsigned long long myKey = ~0ULL; float myMinW = INF_F;
        #pragma unroll
        for (int j = 0; j < 4; ++j) {
            // nonneg float bits order-preserving: min key == (min d, then min n) == first-min
            unsigned long long kj =
                ((unsigned long long)__float_as_uint(bestD[j]) << 6) | (unsigned)bestN[j];
            float wj = minW[j];
            #pragma unroll
            for (int m = 1; m < 8; m <<= 1) {
                const unsigned long long o = __shfl_xor(kj, m);
                kj = o < kj ? o : kj;
                wj = fminf(wj, __shfl_xor(wj, m));
            }
            if (su == j) { myKey = kj; myMinW = wj; }
        }

        float neg_term = 0.f, reg_term = 0.f, reg_val = 0.f;
        if (su < 4) {
            const int myloc = locBase + su;
            float hmv = expf(-myMinW);
            if (hmv < 1e-4f) hmv = 0.0f;
            const float u = 1.0f - hmv;
            const float neg_w = (u * u) * (u * u);
            const float z = agn[myloc];
            float pr = 1.0f / (1.0f + expf(-z));
            pr = fminf(fmaxf(pr, 1e-4f), 1.0f - 1e-4f);
            if (pr < 0.85f) neg_term = logf(1.0f - pr) * (pr * pr) * neg_w;

            if ((unsigned)(myKey >> 6) < __float_as_uint(INF_F)) {
                reg_val = 1.0f;
                const int n = (int)(myKey & 63);
                const float4 A = sBox[imgBase + n];
                const int   p  = (myloc - LB) & ((1 << lsh) - 1);
                const float gx = (float)(p & ((1 << wsh) - 1)) * s + half;
                const float gy = (float)(p >> wsh) * s + half;
                const float tl  = (gx - A.x) * inv_s;    // bit-exact vs /s
                const float tt2 = (gy - A.y) * inv_s;
                const float tr  = (A.z - gx) * inv_s;
                const float tb  = (A.w - gy) * inv_s;
                const float4 pv = ((const float4*)reg_pred)[myloc];
                const float pl = pv.x, pt = pv.y, prr = pv.z, pb = pv.w;
                const float target_area = (tl + tr) * (tt2 + tb);
                const float pred_area   = (pl + prr) * (pt + pb);
                const float w_i = fminf(pl, tl) + fminf(prr, tr);
                const float g_w = fmaxf(pl, tl) + fmaxf(prr, tr);
                const float h_i = fminf(pb, tb) + fminf(pt, tt2);
                const float g_h = fmaxf(pb, tb) + fmaxf(pt, tt2);
                const float ac    = g_w * g_h + 1e-7f;
                const float inter = w_i * h_i;
                const float uni   = target_area + pred_area - inter;
                const float ious  = (inter + 1.0f) / (uni + 1.0f);
                const float gious = ious - (ac - uni) / ac;
                reg_term = 1.0f - gious;
            }
        }

        float r0 = reg_term, r1 = reg_val, r2 = neg_term;
        for (int off = 32; off; off >>= 1) {
            r0 += __shfl_down(r0, off);
            r1 += __shfl_down(r1, off);
            r2 += __shfl_down(r2, off);
        }
        if ((t & 63) == 0) {
            const int w = t >> 6;
            sRed[w * 3 + 0] = r0; sRed[w * 3 + 1] = r1; sRed[w * 3 + 2] = r2;
        }
        __syncthreads();
        if (t == 0) {
            ws[4 + blk]             = sRed[0] + sRed[3] + sRed[6] + sRed[9];
            ws[4 + NMAIN + blk]     = sRed[1] + sRed[4] + sRed[7] + sRed[10];
            ws[4 + 2 * NMAIN + blk] = sRed[2] + sRed[5] + sRed[8] + sRed[11];
        }
    }

    // ---- arrive; last block finalizes ----
    __syncthreads();
    if (t == 0) {
        __threadfence();                                 // release partials (device scope)
        const int old = atomicAdd((int*)ws, 1);
        sLast = (old == NMAIN);                          // NMAIN+1 blocks total
    }
    __syncthreads();
    if (!sLast) return;
    __threadfence();                                     // acquire

    float racc = 0.f, cacc = 0.f, nacc = 0.f;
    for (int j = t; j < NMAIN; j += 256) {
        racc += ws[4 + j];
        cacc += ws[4 + NMAIN + j];
        nacc += ws[4 + 2 * NMAIN + j];
    }
    for (int off = 32; off; off >>= 1) {
        racc += __shfl_down(racc, off);
        cacc += __shfl_down(cacc, off);
        nacc += __shfl_down(nacc, off);
    }
    __shared__ float sr[4][3];
    if ((t & 63) == 0) {
        const int w = t >> 6;
        sr[w][0] = racc; sr[w][1] = cacc; sr[w][2] = nacc;
    }
    __syncthreads();
    if (t == 0) {
        const float RS = sr[0][0] + sr[1][0] + sr[2][0] + sr[3][0];
        const float RC = sr[0][1] + sr[1][1] + sr[2][1] + sr[3][1];
        const float NS = sr[0][2] + sr[1][2] + sr[2][2] + sr[3][2];
        const float PS = ws[4 + 3 * NMAIN];
        const float PC = ws[4 + 3 * NMAIN + 1];
        const float num_pos  = fmaxf(PC, 1.0f);
        const float reg_norm = fmaxf(RC, 1.0f);
        out[0] = RS / reg_norm;                     // REG_WEIGHT = 1
        out[1] = 0.5f * (0.25f * -PS) / num_pos;    // POS_W * ALPHA
        out[2] = 0.5f * (0.75f * -NS) / num_pos;    // NEG_W * (1-ALPHA)
    }
}

extern "C" void kernel_launch(void* const* d_in, const int* in_sizes, int n_in,
                              void* d_out, int out_size, void* d_ws, size_t ws_size,
                              hipStream_t stream) {
    const float* boxes    = (const float*)d_in[0];   // [4,64,4] f32
    // d_in[1] = gt_classes (unused)
    const float* agn      = (const float*)d_in[2];   // [87296] f32
    const float* reg_pred = (const float*)d_in[3];   // [87296,4] f32
    float* out = (float*)d_out;
    float* ws  = (float*)d_ws;

    hipMemsetAsync(d_ws, 0, 4, stream);              // zero completion counter
    fused_kernel<<<NMAIN + 1, 256, 0, stream>>>(boxes, agn, reg_pred, ws, out);
}

// Round 7
// 69.331 us; speedup vs baseline: 1.1740x; 1.1740x over previous
//
#include <hip/hip_runtime.h>
#include <math.h>

#define M_TOT 87296
#define NMAIN 682           // main blocks, 128 locations each; block NMAIN = pos-terms
#define INF_F 100000000.0f

// ws layout (floats):
//   [0        .. NMAIN)      per-block reg_sum
//   [NMAIN    .. 2*NMAIN)    per-block reg_cnt
//   [2*NMAIN  .. 3*NMAIN)    per-block neg_sum
//   [3*NMAIN], [3*NMAIN+1]   psum, pcnt (from pos-terms block)
// No counter/fence: finalize is a separate dispatch (stream-ordered, coherent at kernel boundary).

__global__ __launch_bounds__(256, 2) void main_kernel(
    const float* __restrict__ boxes,     // [4,64,4]
    const float* __restrict__ agn,       // [M_TOT]
    const float* __restrict__ reg_pred,  // [M_TOT,4]
    float* __restrict__ ws)
{
    __shared__ float4 sBox[256];
    __shared__ float  sRed[16];

    const int t   = threadIdx.x;
    const int blk = blockIdx.x;

    const int   LB_[5]   = {0, 65536, 81920, 86016, 87040};
    const int   locSh[5] = {14, 12, 10, 8, 6};
    const int   wSh[5]   = {7, 6, 5, 4, 3};
    const float SV[5]    = {8.f, 16.f, 32.f, 64.f, 128.f};
    const float LOv[5]   = {0.f, 64.f, 128.f, 256.f, 512.f};
    const float HIv[5]   = {80.f, 160.f, 320.f, 640.f, 10000000.f};

    if (blk == NMAIN) {
        // ---- pos-terms block (independent of the assignment) ----
        const int   LOC[5] = {16384, 4096, 1024, 256, 64};
        const int   WW[5]  = {128, 64, 32, 16, 8};
        float psum = 0.f, pcnt = 0.f;
        for (int j = t; j < 1280; j += 256) {     // [B,N,L] flattened, L fastest
            const int lev = j % 5;
            const int bn  = j / 5;
            const int b   = bn >> 6;
            const float4 bx = ((const float4*)boxes)[bn];
            const float cx = (bx.x + bx.z) * 0.5f;
            const float cy = (bx.y + bx.w) * 0.5f;
            const int cix = (int)(cx / SV[lev]);
            const int ciy = (int)(cy / SV[lev]);
            int pos = LB_[lev] + b * LOC[lev] + ciy * WW[lev] + cix;
            pos = min(max(pos, 0), M_TOT - 1);
            const float dx = bx.z - bx.x, dy = bx.w - bx.y;
            const float crit = sqrtf(dx * dx + dy * dy) * 0.5f;
            const bool msk = (crit >= LOv[lev]) && (crit <= HIv[lev]);
            const float z = agn[pos];
            float pp = 1.0f / (1.0f + expf(-z));
            pp = fminf(fmaxf(pp, 1e-4f), 1.0f - 1e-4f);
            if (msk) {
                const float om = 1.0f - pp;
                psum += logf(pp) * (om * om);
                pcnt += 1.0f;
            }
        }
        for (int off = 32; off; off >>= 1) {
            psum += __shfl_down(psum, off);
            pcnt += __shfl_down(pcnt, off);
        }
        if ((t & 63) == 0) { sRed[t >> 6] = psum; sRed[4 + (t >> 6)] = pcnt; }
        __syncthreads();
        if (t == 0) {
            ws[3 * NMAIN]     = sRed[0] + sRed[1] + sRed[2] + sRed[3];
            ws[3 * NMAIN + 1] = sRed[4] + sRed[5] + sRed[6] + sRed[7];
        }
        return;
    }

    // ---- main: 128 consecutive locations; 8 subs x 8 boxes x 4 locs per thread ----
    const int mbase = blk << 7;
    int lev;
    if      (mbase < 65536) lev = 0;
    else if (mbase < 81920) lev = 1;
    else if (mbase < 86016) lev = 2;
    else if (mbase < 87040) lev = 3;
    else                    lev = 4;

    const int   LB    = LB_[lev];
    const int   lsh   = locSh[lev];
    const int   wsh   = wSh[lev];
    const float s     = SV[lev];
    const float inv_s = 1.0f / s;      // s is pow2: exact reciprocal
    const float half  = 0.5f * s;
    const float lo    = LOv[lev], hi = HIv[lev];

    sBox[t] = ((const float4*)boxes)[t];     // stage all 256 boxes
    __syncthreads();

    const int g       = t >> 3;              // 32 groups x 4 locations
    const int su      = t & 7;               // sub-lane: boxes su+8k
    const int locBase = mbase + g * 4;       // group's 4 locs lie in ONE image
    const int imgBase = ((locBase - LB) >> lsh) << 6;

    const double DELTA = (1.0 - 0.8) / (1.0 + 0.8);
    const float  RADC  = (float)(DELTA * DELTA * 2.0);

    // register-resident box state; cared hoisted per-box (level-uniform, <=2ulp vs ref)
    float bx1[8], by1[8], bx2[8], by2[8], bcx[8], bcy[8], bqx[8], bqy[8], bir[8];
    int caredMask = 0;
    #pragma unroll
    for (int k = 0; k < 8; ++k) {
        const float4 A = sBox[imgBase + su + 8 * k];
        bx1[k] = A.x; by1[k] = A.y; bx2[k] = A.z; by2[k] = A.w;
        bcx[k] = (A.x + A.z) * 0.5f;
        bcy[k] = (A.y + A.w) * 0.5f;
        bqx[k] = truncf(bcx[k] * inv_s) * s + half;   // int32-trunc semantics, centers>=0
        bqy[k] = truncf(bcy[k] * inv_s) * s + half;
        const float area = (A.z - A.x) * (A.w - A.y);
        bir[k] = 1.0f / fmaxf(RADC * area, 16.0f);
        const float bw = A.z - A.x, bh = A.w - A.y;
        const float crit = sqrtf(bw * bw + bh * bh) * 0.5f;
        caredMask |= ((crit >= lo) && (crit <= hi)) ? (1 << k) : 0;
    }

    float minW[4], bestD[4];
    int   bestN[4];
    #pragma unroll
    for (int j = 0; j < 4; ++j) { minW[j] = INF_F; bestD[j] = INF_F; bestN[j] = 0; }

    #pragma unroll
    for (int j = 0; j < 4; ++j) {
        const int   p  = (locBase + j - LB) & ((1 << lsh) - 1);
        const float gx = (float)(p & ((1 << wsh) - 1)) * s + half;
        const float gy = (float)(p >> wsh) * s + half;
        #pragma unroll
        for (int k = 0; k < 8; ++k) {
            const float l  = gx - bx1[k];
            const float tt = gy - by1[k];
            const float rr = bx2[k] - gx;
            const float bb = by2[k] - gy;
            const bool is_in = fminf(fminf(l, tt), fminf(rr, bb)) > 0.0f;
            const float dx = gx - bqx[k], dy = gy - bqy[k];
            const bool is_peak = (dx * dx + dy * dy) == 0.0f;
            const bool msk = (fabsf(dx) <= s) && (fabsf(dy) <= s) && is_in
                             && ((caredMask >> k) & 1);
            const float ddx = gx - bcx[k], ddy = gy - bcy[k];
            const float dist2 = is_peak ? 0.0f : (ddx * ddx + ddy * ddy);
            const float w2 = dist2 * bir[k];
            minW[j] = fminf(minW[j], w2);
            const float d = msk ? w2 : INF_F;        // w2 < 1e8 always
            if (d < bestD[j]) { bestD[j] = d; bestN[j] = su + 8 * k; }  // ascending n
        }
    }

    // cross-sub reduce per slot j; lane su==j keeps -> lane covers loc locBase+su (su<4)
    unsigned long long myKey = ~0ULL; float myMinW = INF_F;
    #pragma unroll
    for (int j = 0; j < 4; ++j) {
        // nonneg float bits order-preserving: min key == (min d, then min n) == first-min
        unsigned long long kj =
            ((unsigned long long)__float_as_uint(bestD[j]) << 6) | (unsigned)bestN[j];
        float wj = minW[j];
        #pragma unroll
        for (int m = 1; m < 8; m <<= 1) {
            const unsigned long long o = __shfl_xor(kj, m);
            kj = o < kj ? o : kj;
            wj = fminf(wj, __shfl_xor(wj, m));
        }
        if (su == j) { myKey = kj; myMinW = wj; }
    }

    float neg_term = 0.f, reg_term = 0.f, reg_val = 0.f;
    if (su < 4) {
        const int myloc = locBase + su;
        float hmv = expf(-myMinW);
        if (hmv < 1e-4f) hmv = 0.0f;
        const float u = 1.0f - hmv;
        const float neg_w = (u * u) * (u * u);
        const float z = agn[myloc];
        float pr = 1.0f / (1.0f + expf(-z));
        pr = fminf(fmaxf(pr, 1e-4f), 1.0f - 1e-4f);
        if (pr < 0.85f) neg_term = logf(1.0f - pr) * (pr * pr) * neg_w;

        if ((unsigned)(myKey >> 6) < __float_as_uint(INF_F)) {
            reg_val = 1.0f;
            const int n = (int)(myKey & 63);
            const float4 A = sBox[imgBase + n];
            const int   p  = (myloc - LB) & ((1 << lsh) - 1);
            const float gx = (float)(p & ((1 << wsh) - 1)) * s + half;
            const float gy = (float)(p >> wsh) * s + half;
            const float tl  = (gx - A.x) * inv_s;    // bit-exact vs /s
            const float tt2 = (gy - A.y) * inv_s;
            const float tr  = (A.z - gx) * inv_s;
            const float tb  = (A.w - gy) * inv_s;
            const float4 pv = ((const float4*)reg_pred)[myloc];
            const float pl = pv.x, pt = pv.y, prr = pv.z, pb = pv.w;
            const float target_area = (tl + tr) * (tt2 + tb);
            const float pred_area   = (pl + prr) * (pt + pb);
            const float w_i = fminf(pl, tl) + fminf(prr, tr);
            const float g_w = fmaxf(pl, tl) + fmaxf(prr, tr);
            const float h_i = fminf(pb, tb) + fminf(pt, tt2);
            const float g_h = fmaxf(pb, tb) + fmaxf(pt, tt2);
            const float ac    = g_w * g_h + 1e-7f;
            const float inter = w_i * h_i;
            const float uni   = target_area + pred_area - inter;
            const float ious  = (inter + 1.0f) / (uni + 1.0f);
            const float gious = ious - (ac - uni) / ac;
            reg_term = 1.0f - gious;
        }
    }

    float r0 = reg_term, r1 = reg_val, r2 = neg_term;
    for (int off = 32; off; off >>= 1) {
        r0 += __shfl_down(r0, off);
        r1 += __shfl_down(r1, off);
        r2 += __shfl_down(r2, off);
    }
    if ((t & 63) == 0) {
        const int w = t >> 6;
        sRed[w * 3 + 0] = r0; sRed[w * 3 + 1] = r1; sRed[w * 3 + 2] = r2;
    }
    __syncthreads();
    if (t == 0) {
        ws[blk]             = sRed[0] + sRed[3] + sRed[6] + sRed[9];
        ws[NMAIN + blk]     = sRed[1] + sRed[4] + sRed[7] + sRed[10];
        ws[2 * NMAIN + blk] = sRed[2] + sRed[5] + sRed[8] + sRed[11];
    }
}

__global__ __launch_bounds__(256) void finalize(
    const float* __restrict__ ws,
    float* __restrict__ out)
{
    const int t = threadIdx.x;
    float racc = 0.f, cacc = 0.f, nacc = 0.f;
    for (int j = t; j < NMAIN; j += 256) {
        racc += ws[j];
        cacc += ws[NMAIN + j];
        nacc += ws[2 * NMAIN + j];
    }
    for (int off = 32; off; off >>= 1) {
        racc += __shfl_down(racc, off);
        cacc += __shfl_down(cacc, off);
        nacc += __shfl_down(nacc, off);
    }
    __shared__ float sr[4][3];
    if ((t & 63) == 0) {
        const int w = t >> 6;
        sr[w][0] = racc; sr[w][1] = cacc; sr[w][2] = nacc;
    }
    __syncthreads();
    if (t == 0) {
        const float RS = sr[0][0] + sr[1][0] + sr[2][0] + sr[3][0];
        const float RC = sr[0][1] + sr[1][1] + sr[2][1] + sr[3][1];
        const float NS = sr[0][2] + sr[1][2] + sr[2][2] + sr[3][2];
        const float PS = ws[3 * NMAIN];
        const float PC = ws[3 * NMAIN + 1];
        const float num_pos  = fmaxf(PC, 1.0f);
        const float reg_norm = fmaxf(RC, 1.0f);
        out[0] = RS / reg_norm;                     // REG_WEIGHT = 1
        out[1] = 0.5f * (0.25f * -PS) / num_pos;    // POS_W * ALPHA
        out[2] = 0.5f * (0.75f * -NS) / num_pos;    // NEG_W * (1-ALPHA)
    }
}

extern "C" void kernel_launch(void* const* d_in, const int* in_sizes, int n_in,
                              void* d_out, int out_size, void* d_ws, size_t ws_size,
                              hipStream_t stream) {
    const float* boxes    = (const float*)d_in[0];   // [4,64,4] f32
    // d_in[1] = gt_classes (unused)
    const float* agn      = (const float*)d_in[2];   // [87296] f32
    const float* reg_pred = (const float*)d_in[3];   // [87296,4] f32
    float* out = (float*)d_out;
    float* ws  = (float*)d_ws;

    main_kernel<<<NMAIN + 1, 256, 0, stream>>>(boxes, agn, reg_pred, ws);
    finalize<<<1, 256, 0, stream>>>(ws, out);
}